// Round 4
// baseline (1423.348 us; speedup 1.0000x reference)
//
#include <hip/hip_runtime.h>

// ---------------------------------------------------------------------------
// TorchGRUClassifier: 2-layer GRU (B=1024, T=256, I=153, H=128) + MLP head.
// Round 7: inline-asm MFMA consuming AGPR-resident weights directly.
// History: rec kernel is L2-BW-bound re-streaming 288 KB of recurrent
// weights per step (step 4490 cy ~= 288KB / 60 B/cy/CU). Attempts:
//   r4  "+v" pin            -> allocator kept budget 128, remat stayed.
//   r5  launch_bounds(512,2)-> still 128; drain-free barrier won -183 us.
//   r6  "+a" pin + builtin  -> AGPR homes BUT builtin needs VGPR operands:
//       per-use accvgpr_read copies -> spills (WRITE_SIZE 0.6->11.4 MB).
// Fix: ISA says MFMA srcA/srcB may be AGPR on gfx950 (unified file). Inline
// asm `v_mfma_f32_16x16x32_bf16 %0,%1,%2,%0` with "a"(B) reads the weight
// fragment from its AGPR home with ZERO copies. 144 AGPR (weights) +
// ~110 arch VGPR (working set) = 256/wave -> one 8-wave block per CU.
// ---------------------------------------------------------------------------

typedef __bf16 bf16x8 __attribute__((ext_vector_type(8)));
typedef float  f32x4  __attribute__((ext_vector_type(4)));

#define HS 136   // LDS row stride (bf16) for h tiles: 272 B -> uniform banks
#define OS 136   // LDS row stride (bf16) for gi0 output tile (16B-aligned rows)

__device__ __forceinline__ f32x4 mfma16(bf16x8 a, bf16x8 b, f32x4 c) {
    return __builtin_amdgcn_mfma_f32_16x16x32_bf16(a, b, c, 0, 0, 0);
}
// MFMA with B operand read DIRECTLY from an AGPR home (no copy).
__device__ __forceinline__ void mfma16_agpr(f32x4& acc, bf16x8 a, const bf16x8& b) {
    asm("v_mfma_f32_16x16x32_bf16 %0, %1, %2, %0"
        : "+v"(acc) : "v"(a), "a"(b));
}
__device__ __forceinline__ float sigf(float x) {
    return __builtin_amdgcn_rcpf(1.f + __expf(-x));
}
__device__ __forceinline__ float tanhf_(float x) { return 2.f * sigf(2.f * x) - 1.f; }

// Workgroup barrier WITHOUT the vmcnt(0) drain __syncthreads() emits.
__device__ __forceinline__ void barrier_nodrain() {
    asm volatile("s_waitcnt lgkmcnt(0)" ::: "memory");
    __builtin_amdgcn_s_barrier();
    asm volatile("" ::: "memory");
}

// ---- prep: cast weights to bf16 (W_ih0 padded K 153->160 with zeros) ------
__global__ void prep_w_kernel(const float* __restrict__ Wih0, const float* __restrict__ Whh0,
                              const float* __restrict__ Wih1, const float* __restrict__ Whh1,
                              __bf16* __restrict__ o_ih0, __bf16* __restrict__ o_hh0,
                              __bf16* __restrict__ o_ih1, __bf16* __restrict__ o_hh1) {
    int idx = blockIdx.x * 256 + threadIdx.x;      // grid covers 384*160 = 61440
    if (idx < 384 * 160) {
        int n = idx / 160, k = idx - n * 160;
        o_ih0[idx] = (__bf16)(k < 153 ? Wih0[n * 153 + k] : 0.f);
    }
    if (idx < 384 * 128) {
        o_hh0[idx] = (__bf16)Whh0[idx];
        o_ih1[idx] = (__bf16)Wih1[idx];
        o_hh1[idx] = (__bf16)Whh1[idx];
    }
}

// ---- gi0 GEMM: [262144,153(pad160)] x [160,384] -> gi0 bf16 [262144][384] --
__global__ __launch_bounds__(512, 2) void gi0_gemm_kernel(
    const float* __restrict__ x, const __bf16* __restrict__ Wih0b,
    __bf16* __restrict__ gi0)
{
    __shared__ __align__(16) __bf16 smem[128 * 160];   // As (40KB), reused as Os
    const int r0  = blockIdx.x * 128;
    const int tid = threadIdx.x;
    const int w = tid >> 6, lane = tid & 63, q = lane >> 4, c15 = lane & 15;

    // B fragments first: these global loads overlap the x staging below.
    bf16x8 bf[3][5];
    #pragma unroll
    for (int j = 0; j < 3; ++j) {
        int colb = 16 * (w + 8 * j) + c15;
        #pragma unroll
        for (int ks = 0; ks < 5; ++ks)
            bf[j][ks] = *(const bf16x8*)(Wih0b + colb * 160 + ks * 32 + q * 8);
    }

    for (int e = tid; e < 128 * 160; e += 512) {
        int r = e / 160, c = e - r * 160;
        float v = (c < 153) ? x[(size_t)(r0 + r) * 153 + c] : 0.f;
        smem[e] = (__bf16)v;
    }
    __syncthreads();

    f32x4 acc[8][3];
    #pragma unroll
    for (int rt = 0; rt < 8; ++rt)
        #pragma unroll
        for (int j = 0; j < 3; ++j) acc[rt][j] = (f32x4){0.f, 0.f, 0.f, 0.f};

    #pragma unroll
    for (int ks = 0; ks < 5; ++ks) {
        bf16x8 a[8];
        #pragma unroll
        for (int rt = 0; rt < 8; ++rt)
            a[rt] = *(const bf16x8*)(&smem[(rt * 16 + c15) * 160 + ks * 32 + q * 8]);
        #pragma unroll
        for (int rt = 0; rt < 8; ++rt)
            #pragma unroll
            for (int j = 0; j < 3; ++j) acc[rt][j] = mfma16(a[rt], bf[j][ks], acc[rt][j]);
    }
    __syncthreads();   // done reading As; reuse as Os
    #pragma unroll
    for (int j = 0; j < 3; ++j) {
        #pragma unroll
        for (int rt = 0; rt < 8; ++rt)
            #pragma unroll
            for (int r = 0; r < 4; ++r)
                smem[(rt * 16 + q * 4 + r) * OS + 16 * w + c15] = (__bf16)acc[rt][j][r];
        __syncthreads();
        #pragma unroll
        for (int pass = 0; pass < 4; ++pass) {
            int row = pass * 32 + (tid >> 4);
            int col = (tid & 15) * 8;
            bf16x8 v = *(const bf16x8*)(&smem[row * OS + col]);
            *(bf16x8*)(gi0 + (size_t)(r0 + row) * 384 + j * 128 + col) = v;
        }
        if (j < 2) __syncthreads();
    }
}

// ---- fused recurrence + head ----------------------------------------------
// Weights: 36 bf16x8 fragments homed in AGPRs (144 AGPRs), consumed in-place
// by inline-asm MFMA. Arch VGPRs hold only the ~110-reg working set.
__global__ __launch_bounds__(512, 2)
void gru_rec_kernel(
    const __bf16* __restrict__ gi0,
    const __bf16* __restrict__ Whh0, const __bf16* __restrict__ Wih1,
    const __bf16* __restrict__ Whh1,
    const float* __restrict__ b_ih0, const float* __restrict__ b_hh0,
    const float* __restrict__ b_ih1, const float* __restrict__ b_hh1,
    const float* __restrict__ W1, const float* __restrict__ b1,
    const float* __restrict__ W2, const float* __restrict__ b2,
    float* __restrict__ out)
{
    __shared__ __align__(16) __bf16 h0sA[16 * HS], h0sB[16 * HS];
    __shared__ __align__(16) __bf16 h1sA[16 * HS], h1sB[16 * HS];
    __shared__ float h1f[16 * 128];
    __shared__ float hdnf[16 * 64];

    const int tid  = threadIdx.x;
    const int w    = tid >> 6;
    const int lane = tid & 63;
    const int q    = lane >> 4;
    const int c15  = lane & 15;
    const int c_col = w * 16 + c15;   // gate/hidden column this lane owns
    const int b0   = blockIdx.x * 16;

    // --- weight B-fragments -> AGPR homes (36 frags = 144 AGPRs) -----------
    bf16x8 fhh0[3][4], fih1[3][4], fhh1[3][4];
    #pragma unroll
    for (int g = 0; g < 3; ++g) {
        int row = g * 128 + c_col;
        #pragma unroll
        for (int ks = 0; ks < 4; ++ks) {
            size_t off = (size_t)row * 128 + ks * 32 + q * 8;
            fhh0[g][ks] = *(const bf16x8*)(Whh0 + off);
            fih1[g][ks] = *(const bf16x8*)(Wih1 + off);
            fhh1[g][ks] = *(const bf16x8*)(Whh1 + off);
        }
    }
    // One-time v->a copy; origin becomes the asm so no remat is possible.
    // All consumers use the "a" constraint -> no per-use copies (r6 bug).
    #pragma unroll
    for (int g = 0; g < 3; ++g)
        #pragma unroll
        for (int ks = 0; ks < 4; ++ks) {
            asm volatile("" : "+a"(fhh0[g][ks]));
            asm volatile("" : "+a"(fih1[g][ks]));
            asm volatile("" : "+a"(fhh1[g][ks]));
        }

    // biases: r,z gates use (b_ih + b_hh) combined; n gate keeps them split
    float B0rz[2], B1rz[2], bi0n, bh0n, bi1n, bh1n;
    B0rz[0] = b_ih0[c_col] + b_hh0[c_col];
    B0rz[1] = b_ih0[128 + c_col] + b_hh0[128 + c_col];
    B1rz[0] = b_ih1[c_col] + b_hh1[c_col];
    B1rz[1] = b_ih1[128 + c_col] + b_hh1[128 + c_col];
    bi0n = b_ih0[256 + c_col]; bh0n = b_hh0[256 + c_col];
    bi1n = b_ih1[256 + c_col]; bh1n = b_hh1[256 + c_col];

    float h0r[4] = {0.f, 0.f, 0.f, 0.f};
    float h1r[4] = {0.f, 0.f, 0.f, 0.f};
    for (int i = tid; i < 16 * HS; i += 512) {
        h0sA[i] = (__bf16)0.f; h0sB[i] = (__bf16)0.f;
        h1sA[i] = (__bf16)0.f; h1sB[i] = (__bf16)0.f;
    }
    __syncthreads();

    // gi0 offsets (32-bit, elements): rows (b0+q*4+r), stepping t -> +384
    unsigned goff[4];
    #pragma unroll
    for (int r = 0; r < 4; ++r)
        goff[r] = (unsigned)(b0 + q * 4 + r) * 256u * 384u + (unsigned)c_col;

    // gi0 prefetch double-buffer (role-swapped each step; no rotation movs)
    __bf16 givA[4][3], givB[4][3];
    #pragma unroll
    for (int r = 0; r < 4; ++r)
        #pragma unroll
        for (int g = 0; g < 3; ++g) givA[r][g] = gi0[goff[r] + g * 128];
    #pragma unroll
    for (int r = 0; r < 4; ++r) goff[r] += 384;

    // one step; ONE (drain-free) barrier
    auto do_step = [&](const __bf16* h0rd, __bf16* h0wr,
                       const __bf16* h1rd, __bf16* h1wr,
                       __bf16 (&gvRd)[4][3], __bf16 (&gvWr)[4][3]) {
        // prefetch NEXT step's gi0 (in flight across the drain-free barrier;
        // final step over-reads 1 row into the mapped weight region, unused)
        #pragma unroll
        for (int r = 0; r < 4; ++r)
            #pragma unroll
            for (int g = 0; g < 3; ++g) gvWr[r][g] = gi0[goff[r] + g * 128];
        #pragma unroll
        for (int r = 0; r < 4; ++r) goff[r] += 384;

        // gh0 = h0 @ Whh0^T   (B operands streamed from AGPR homes)
        f32x4 hacc[3];
        #pragma unroll
        for (int g = 0; g < 3; ++g) hacc[g] = (f32x4){0.f, 0.f, 0.f, 0.f};
        #pragma unroll
        for (int ks = 0; ks < 4; ++ks) {
            bf16x8 a = *(const bf16x8*)(h0rd + c15 * HS + ks * 32 + q * 8);
            #pragma unroll
            for (int g = 0; g < 3; ++g) mfma16_agpr(hacc[g], a, fhh0[g][ks]);
        }
        // layer-0 gates -> h0wr
        #pragma unroll
        for (int r = 0; r < 4; ++r) {
            float rr = sigf((float)gvRd[r][0] + hacc[0][r] + B0rz[0]);
            float zz = sigf((float)gvRd[r][1] + hacc[1][r] + B0rz[1]);
            float nn = tanhf_((float)gvRd[r][2] + bi0n + rr * (hacc[2][r] + bh0n));
            float hnew = zz * (h0r[r] - nn) + nn;
            h0r[r] = hnew;
            h0wr[(q * 4 + r) * HS + c_col] = (__bf16)hnew;
        }
        barrier_nodrain();   // the ONLY barrier this step (no vmcnt drain)
        // gi1 = h0_new @ Wih1^T ; gh1 = h1 @ Whh1^T
        f32x4 iacc[3], hacc1[3];
        #pragma unroll
        for (int g = 0; g < 3; ++g) {
            iacc[g]  = (f32x4){0.f, 0.f, 0.f, 0.f};
            hacc1[g] = (f32x4){0.f, 0.f, 0.f, 0.f};
        }
        #pragma unroll
        for (int ks = 0; ks < 4; ++ks) {
            bf16x8 a0 = *(const bf16x8*)(h0wr + c15 * HS + ks * 32 + q * 8);
            bf16x8 a1 = *(const bf16x8*)(h1rd + c15 * HS + ks * 32 + q * 8);
            #pragma unroll
            for (int g = 0; g < 3; ++g) {
                mfma16_agpr(iacc[g],  a0, fih1[g][ks]);
                mfma16_agpr(hacc1[g], a1, fhh1[g][ks]);
            }
        }
        // layer-1 gates -> h1wr
        #pragma unroll
        for (int r = 0; r < 4; ++r) {
            float rr = sigf(iacc[0][r] + hacc1[0][r] + B1rz[0]);
            float zz = sigf(iacc[1][r] + hacc1[1][r] + B1rz[1]);
            float nn = tanhf_(iacc[2][r] + bi1n + rr * (hacc1[2][r] + bh1n));
            float hnew = zz * (h1r[r] - nn) + nn;
            h1r[r] = hnew;
            h1wr[(q * 4 + r) * HS + c_col] = (__bf16)hnew;
        }
    };

    for (int tt = 0; tt < 128; ++tt) {
        do_step(h0sA, h0sB, h1sA, h1sB, givA, givB);   // even t
        do_step(h0sB, h0sA, h1sB, h1sA, givB, givA);   // odd  t
    }

    // ---- head: relu(h1 @ W1^T + b1) @ W2^T + b2 -> sigmoid ----------------
    #pragma unroll
    for (int r = 0; r < 4; ++r) h1f[(q * 4 + r) * 128 + c_col] = h1r[r];
    __syncthreads();
    for (int p = tid; p < 16 * 64; p += 512) {
        int m = p >> 6, u = p & 63;
        float s = b1[u];
        const float* hrow = &h1f[m * 128];
        const float* wrow = &W1[u * 128];
        #pragma unroll 8
        for (int k = 0; k < 128; ++k) s += hrow[k] * wrow[k];
        hdnf[p] = fmaxf(s, 0.f);
    }
    __syncthreads();
    if (tid < 16) {
        float s = b2[0];
        #pragma unroll 8
        for (int k = 0; k < 64; ++k) s += hdnf[tid * 64 + k] * W2[k];
        out[b0 + tid] = sigf(s);
    }
}

// ---------------------------------------------------------------------------
extern "C" void kernel_launch(void* const* d_in, const int* in_sizes, int n_in,
                              void* d_out, int out_size, void* d_ws, size_t ws_size,
                              hipStream_t stream) {
    const float* x     = (const float*)d_in[0];
    const float* W_ih0 = (const float*)d_in[1];
    const float* W_hh0 = (const float*)d_in[2];
    const float* bih0  = (const float*)d_in[3];
    const float* bhh0  = (const float*)d_in[4];
    const float* W_ih1 = (const float*)d_in[5];
    const float* W_hh1 = (const float*)d_in[6];
    const float* bih1  = (const float*)d_in[7];
    const float* bhh1  = (const float*)d_in[8];
    const float* W1    = (const float*)d_in[9];
    const float* b1    = (const float*)d_in[10];
    const float* W2    = (const float*)d_in[11];
    const float* b2    = (const float*)d_in[12];
    float* out = (float*)d_out;

    char* ws = (char*)d_ws;
    // ws layout (bytes):
    //   gi0   : 262144 x 384 bf16 = 201,326,592   @ 0
    //   Wih0b : 384x160 bf16      =     122,880   @ 201326592
    //   Whh0b / Wih1b / Whh1b : 384x128 bf16 = 98,304 each
    __bf16* gi0   = (__bf16*)(ws);
    __bf16* wih0b = (__bf16*)(ws + 201326592);
    __bf16* whh0b = (__bf16*)(ws + 201449472);
    __bf16* wih1b = (__bf16*)(ws + 201547776);
    __bf16* whh1b = (__bf16*)(ws + 201646080);

    prep_w_kernel<<<240, 256, 0, stream>>>(W_ih0, W_hh0, W_ih1, W_hh1,
                                           wih0b, whh0b, wih1b, whh1b);
    gi0_gemm_kernel<<<2048, 512, 0, stream>>>(x, wih0b, gi0);
    gru_rec_kernel<<<64, 512, 0, stream>>>(gi0, whh0b, wih1b, whh1b,
                                           bih0, bhh0, bih1, bhh1,
                                           W1, b1, W2, b2, out);
}

// Round 5
// 932.234 us; speedup vs baseline: 1.5268x; 1.5268x over previous
//
#include <hip/hip_runtime.h>

// ---------------------------------------------------------------------------
// TorchGRUClassifier: 2-layer GRU (B=1024, T=256, I=153, H=128) + MLP head.
// Round 8: LAYER SPLIT. Rounds 4-7 proved the allocator will not keep >128
// useful regs/wave (remat at 124/128; AGPR homing -> 18.4 MB scratch spills,
// exactly 144 regs x 64 lanes x 512 waves). The fused rec kernel needs 144
// weight regs/wave -> per-step 288 KB L2 re-stream -> 4490 cy/step.
// Fix: split so each recurrent kernel needs only ONE weight matrix
// (3 tiles = 48 regs/wave, total demand ~120 < 128 -> truly resident):
//   rec0:   layer-0 recurrence; writes h0_t in-place into gi0 row (b,t)
//           (cols 0..127) right after that row is consumed.
//   gi1_gemm: h0 [262144x128] @ Wih1^T -> gi1 [262144x384], in-place per row
//           (A staged to LDS before overwrite). Layer-1 input projection
//           becomes a parallel GEMM instead of serial per-step MFMA.
//   rec1:   layer-1 recurrence + MLP head.
// Workspace layout unchanged (201.6 MB).
// ---------------------------------------------------------------------------

typedef __bf16 bf16x8 __attribute__((ext_vector_type(8)));
typedef __bf16 bf16x4 __attribute__((ext_vector_type(4)));
typedef float  f32x4  __attribute__((ext_vector_type(4)));

#define HS 136   // LDS row stride (bf16): 272 B -> 2-way bank aliasing (free)
#define OS 136

__device__ __forceinline__ f32x4 mfma16(bf16x8 a, bf16x8 b, f32x4 c) {
    return __builtin_amdgcn_mfma_f32_16x16x32_bf16(a, b, c, 0, 0, 0);
}
__device__ __forceinline__ float sigf(float x) {
    return __builtin_amdgcn_rcpf(1.f + __expf(-x));
}
__device__ __forceinline__ float tanhf_(float x) { return 2.f * sigf(2.f * x) - 1.f; }

// Workgroup barrier WITHOUT the vmcnt(0) drain __syncthreads() emits:
// outstanding global loads (gi prefetch) stay in flight across it.
__device__ __forceinline__ void barrier_nodrain() {
    asm volatile("s_waitcnt lgkmcnt(0)" ::: "memory");
    __builtin_amdgcn_s_barrier();
    asm volatile("" ::: "memory");
}

// ---- prep: cast weights to bf16 (W_ih0 padded K 153->160 with zeros) ------
__global__ void prep_w_kernel(const float* __restrict__ Wih0, const float* __restrict__ Whh0,
                              const float* __restrict__ Wih1, const float* __restrict__ Whh1,
                              __bf16* __restrict__ o_ih0, __bf16* __restrict__ o_hh0,
                              __bf16* __restrict__ o_ih1, __bf16* __restrict__ o_hh1) {
    int idx = blockIdx.x * 256 + threadIdx.x;      // grid covers 384*160 = 61440
    if (idx < 384 * 160) {
        int n = idx / 160, k = idx - n * 160;
        o_ih0[idx] = (__bf16)(k < 153 ? Wih0[n * 153 + k] : 0.f);
    }
    if (idx < 384 * 128) {
        o_hh0[idx] = (__bf16)Whh0[idx];
        o_ih1[idx] = (__bf16)Wih1[idx];
        o_hh1[idx] = (__bf16)Whh1[idx];
    }
}

// ---- gi0 GEMM: [262144,153(pad160)] x [160,384] -> gi0 bf16 [262144][384] --
__global__ __launch_bounds__(512, 2) void gi0_gemm_kernel(
    const float* __restrict__ x, const __bf16* __restrict__ Wih0b,
    __bf16* __restrict__ gi0)
{
    __shared__ __align__(16) __bf16 smem[128 * 160];   // As (40KB), reused as Os
    const int r0  = blockIdx.x * 128;
    const int tid = threadIdx.x;
    const int w = tid >> 6, lane = tid & 63, q = lane >> 4, c15 = lane & 15;

    // B fragments first: these global loads overlap the x staging below.
    bf16x8 bf[3][5];
    #pragma unroll
    for (int j = 0; j < 3; ++j) {
        int colb = 16 * (w + 8 * j) + c15;
        #pragma unroll
        for (int ks = 0; ks < 5; ++ks)
            bf[j][ks] = *(const bf16x8*)(Wih0b + colb * 160 + ks * 32 + q * 8);
    }

    for (int e = tid; e < 128 * 160; e += 512) {
        int r = e / 160, c = e - r * 160;
        float v = (c < 153) ? x[(size_t)(r0 + r) * 153 + c] : 0.f;
        smem[e] = (__bf16)v;
    }
    __syncthreads();

    f32x4 acc[8][3];
    #pragma unroll
    for (int rt = 0; rt < 8; ++rt)
        #pragma unroll
        for (int j = 0; j < 3; ++j) acc[rt][j] = (f32x4){0.f, 0.f, 0.f, 0.f};

    #pragma unroll
    for (int ks = 0; ks < 5; ++ks) {
        bf16x8 a[8];
        #pragma unroll
        for (int rt = 0; rt < 8; ++rt)
            a[rt] = *(const bf16x8*)(&smem[(rt * 16 + c15) * 160 + ks * 32 + q * 8]);
        #pragma unroll
        for (int rt = 0; rt < 8; ++rt)
            #pragma unroll
            for (int j = 0; j < 3; ++j) acc[rt][j] = mfma16(a[rt], bf[j][ks], acc[rt][j]);
    }
    __syncthreads();   // done reading As; reuse as Os
    #pragma unroll
    for (int j = 0; j < 3; ++j) {
        #pragma unroll
        for (int rt = 0; rt < 8; ++rt)
            #pragma unroll
            for (int r = 0; r < 4; ++r)
                smem[(rt * 16 + q * 4 + r) * OS + 16 * w + c15] = (__bf16)acc[rt][j][r];
        __syncthreads();
        #pragma unroll
        for (int pass = 0; pass < 4; ++pass) {
            int row = pass * 32 + (tid >> 4);
            int col = (tid & 15) * 8;
            bf16x8 v = *(const bf16x8*)(&smem[row * OS + col]);
            *(bf16x8*)(gi0 + (size_t)(r0 + row) * 384 + j * 128 + col) = v;
        }
        if (j < 2) __syncthreads();
    }
}

// ---- rec0: layer-0 recurrence; h0_t written in-place into gio rows --------
// Per wave: Whh0 fragments only (3 tiles = 48 VGPRs) -> total demand ~120.
__global__ __launch_bounds__(512, 2)
void gru_rec0_kernel(__bf16* __restrict__ gio,      // gi0 in; h0 out (cols 0..127 of each row)
                     const __bf16* __restrict__ Whh0,
                     const float* __restrict__ b_ih0, const float* __restrict__ b_hh0)
{
    __shared__ __align__(16) __bf16 hsA[16 * HS], hsB[16 * HS];

    const int tid  = threadIdx.x;
    const int w    = tid >> 6;
    const int lane = tid & 63;
    const int q    = lane >> 4;
    const int c15  = lane & 15;
    const int c_col = w * 16 + c15;
    const int b0   = blockIdx.x * 16;

    bf16x8 fhh[3][4];
    #pragma unroll
    for (int g = 0; g < 3; ++g)
        #pragma unroll
        for (int ks = 0; ks < 4; ++ks)
            fhh[g][ks] = *(const bf16x8*)(Whh0 + (size_t)(g * 128 + c_col) * 128 + ks * 32 + q * 8);

    float Brz[2], bin, bhn;
    Brz[0] = b_ih0[c_col] + b_hh0[c_col];
    Brz[1] = b_ih0[128 + c_col] + b_hh0[128 + c_col];
    bin = b_ih0[256 + c_col]; bhn = b_hh0[256 + c_col];

    float hr[4] = {0.f, 0.f, 0.f, 0.f};
    for (int i = tid; i < 16 * HS; i += 512) { hsA[i] = (__bf16)0.f; hsB[i] = (__bf16)0.f; }
    __syncthreads();

    unsigned goff[4];
    #pragma unroll
    for (int r = 0; r < 4; ++r)
        goff[r] = (unsigned)(b0 + q * 4 + r) * 98304u + (unsigned)c_col;   // 98304 = 256*384

    __bf16 gvA[4][3], gvB[4][3];
    #pragma unroll
    for (int r = 0; r < 4; ++r)
        #pragma unroll
        for (int g = 0; g < 3; ++g) gvA[r][g] = gio[goff[r] + g * 128];
    #pragma unroll
    for (int r = 0; r < 4; ++r) goff[r] += 384;

    // h-store mapping: thread -> (row srow, 4 cols at scol) of the 16x128 tile
    const int srow = tid >> 5;            // 0..15
    const int scol = (tid & 31) * 4;      // 0..124
    const size_t sbase = (size_t)(b0 + srow) * 98304u + scol;

    auto step = [&](const __bf16* rd, __bf16* wr,
                    __bf16 (&gR)[4][3], __bf16 (&gW)[4][3], int t) {
        // prefetch next step's gi0 (in flight across the drain-free barrier;
        // t=255 over-reads into next batch's rows / weight region: harmless)
        #pragma unroll
        for (int r = 0; r < 4; ++r)
            #pragma unroll
            for (int g = 0; g < 3; ++g) gW[r][g] = gio[goff[r] + g * 128];
        #pragma unroll
        for (int r = 0; r < 4; ++r) goff[r] += 384;

        f32x4 hacc[3];
        #pragma unroll
        for (int g = 0; g < 3; ++g) hacc[g] = (f32x4){0.f, 0.f, 0.f, 0.f};
        #pragma unroll
        for (int ks = 0; ks < 4; ++ks) {
            bf16x8 a = *(const bf16x8*)(rd + c15 * HS + ks * 32 + q * 8);
            #pragma unroll
            for (int g = 0; g < 3; ++g) hacc[g] = mfma16(a, fhh[g][ks], hacc[g]);
        }
        #pragma unroll
        for (int r = 0; r < 4; ++r) {
            float rr = sigf((float)gR[r][0] + hacc[0][r] + Brz[0]);
            float zz = sigf((float)gR[r][1] + hacc[1][r] + Brz[1]);
            float nn = tanhf_((float)gR[r][2] + bin + rr * (hacc[2][r] + bhn));
            float hnew = zz * (hr[r] - nn) + nn;
            hr[r] = hnew;
            wr[(q * 4 + r) * HS + c_col] = (__bf16)hnew;
        }
        barrier_nodrain();
        // h0_t -> gio row (b,t) cols 0..127. Safe: row t's prefetch was
        // vmcnt-consumed before this barrier; only this block owns these rows.
        bf16x4 hv = *(const bf16x4*)(wr + srow * HS + scol);
        *(bf16x4*)(gio + sbase + (size_t)t * 384) = hv;
    };

    for (int tt = 0; tt < 128; ++tt) {
        step(hsA, hsB, gvA, gvB, 2 * tt);
        step(hsB, hsA, gvB, gvA, 2 * tt + 1);
    }
}

// ---- gi1 GEMM (in-place): rows [0:128]=h0 -> rows [0:384]=gi1 -------------
__global__ __launch_bounds__(512, 2)
void gi1_gemm_kernel(__bf16* __restrict__ gio, const __bf16* __restrict__ Wih1b)
{
    __shared__ __align__(16) __bf16 smem[128 * HS];   // A (34 KB), reused as Os
    const int r0  = blockIdx.x * 128;
    const int tid = threadIdx.x;
    const int w = tid >> 6, lane = tid & 63, q = lane >> 4, c15 = lane & 15;

    // B fragments (overlap A staging)
    bf16x8 bf[3][4];
    #pragma unroll
    for (int j = 0; j < 3; ++j) {
        int colb = 16 * (w + 8 * j) + c15;
        #pragma unroll
        for (int ks = 0; ks < 4; ++ks)
            bf[j][ks] = *(const bf16x8*)(Wih1b + (size_t)colb * 128 + ks * 32 + q * 8);
    }

    // stage A: 128 rows x 128 cols bf16, vectorized 16B chunks
    for (int cidx = tid; cidx < 2048; cidx += 512) {
        int row = cidx >> 4, c8 = (cidx & 15) * 8;
        *(bf16x8*)&smem[row * HS + c8] =
            *(const bf16x8*)(gio + (size_t)(r0 + row) * 384 + c8);
    }
    __syncthreads();

    f32x4 acc[8][3];
    #pragma unroll
    for (int rt = 0; rt < 8; ++rt)
        #pragma unroll
        for (int j = 0; j < 3; ++j) acc[rt][j] = (f32x4){0.f, 0.f, 0.f, 0.f};

    #pragma unroll
    for (int ks = 0; ks < 4; ++ks) {
        bf16x8 a[8];
        #pragma unroll
        for (int rt = 0; rt < 8; ++rt)
            a[rt] = *(const bf16x8*)(&smem[(rt * 16 + c15) * HS + ks * 32 + q * 8]);
        #pragma unroll
        for (int rt = 0; rt < 8; ++rt)
            #pragma unroll
            for (int j = 0; j < 3; ++j) acc[rt][j] = mfma16(a[rt], bf[j][ks], acc[rt][j]);
    }
    __syncthreads();   // done reading A; rows may now be overwritten
    #pragma unroll
    for (int j = 0; j < 3; ++j) {
        #pragma unroll
        for (int rt = 0; rt < 8; ++rt)
            #pragma unroll
            for (int r = 0; r < 4; ++r)
                smem[(rt * 16 + q * 4 + r) * OS + 16 * w + c15] = (__bf16)acc[rt][j][r];
        __syncthreads();
        #pragma unroll
        for (int pass = 0; pass < 4; ++pass) {
            int row = pass * 32 + (tid >> 4);
            int col = (tid & 15) * 8;
            bf16x8 v = *(const bf16x8*)(&smem[row * OS + col]);
            *(bf16x8*)(gio + (size_t)(r0 + row) * 384 + j * 128 + col) = v;
        }
        if (j < 2) __syncthreads();
    }
}

// ---- rec1: layer-1 recurrence + MLP head ----------------------------------
__global__ __launch_bounds__(512, 2)
void gru_rec1_kernel(const __bf16* __restrict__ gi1,
                     const __bf16* __restrict__ Whh1,
                     const float* __restrict__ b_ih1, const float* __restrict__ b_hh1,
                     const float* __restrict__ W1, const float* __restrict__ b1,
                     const float* __restrict__ W2, const float* __restrict__ b2,
                     float* __restrict__ out)
{
    __shared__ __align__(16) __bf16 hsA[16 * HS], hsB[16 * HS];
    __shared__ float h1f[16 * 128];
    __shared__ float hdnf[16 * 64];

    const int tid  = threadIdx.x;
    const int w    = tid >> 6;
    const int lane = tid & 63;
    const int q    = lane >> 4;
    const int c15  = lane & 15;
    const int c_col = w * 16 + c15;
    const int b0   = blockIdx.x * 16;

    bf16x8 fhh[3][4];
    #pragma unroll
    for (int g = 0; g < 3; ++g)
        #pragma unroll
        for (int ks = 0; ks < 4; ++ks)
            fhh[g][ks] = *(const bf16x8*)(Whh1 + (size_t)(g * 128 + c_col) * 128 + ks * 32 + q * 8);

    float Brz[2], bin, bhn;
    Brz[0] = b_ih1[c_col] + b_hh1[c_col];
    Brz[1] = b_ih1[128 + c_col] + b_hh1[128 + c_col];
    bin = b_ih1[256 + c_col]; bhn = b_hh1[256 + c_col];

    float hr[4] = {0.f, 0.f, 0.f, 0.f};
    for (int i = tid; i < 16 * HS; i += 512) { hsA[i] = (__bf16)0.f; hsB[i] = (__bf16)0.f; }
    __syncthreads();

    unsigned goff[4];
    #pragma unroll
    for (int r = 0; r < 4; ++r)
        goff[r] = (unsigned)(b0 + q * 4 + r) * 98304u + (unsigned)c_col;

    __bf16 gvA[4][3], gvB[4][3];
    #pragma unroll
    for (int r = 0; r < 4; ++r)
        #pragma unroll
        for (int g = 0; g < 3; ++g) gvA[r][g] = gi1[goff[r] + g * 128];
    #pragma unroll
    for (int r = 0; r < 4; ++r) goff[r] += 384;

    auto step = [&](const __bf16* rd, __bf16* wr,
                    __bf16 (&gR)[4][3], __bf16 (&gW)[4][3]) {
        #pragma unroll
        for (int r = 0; r < 4; ++r)
            #pragma unroll
            for (int g = 0; g < 3; ++g) gW[r][g] = gi1[goff[r] + g * 128];
        #pragma unroll
        for (int r = 0; r < 4; ++r) goff[r] += 384;

        f32x4 hacc[3];
        #pragma unroll
        for (int g = 0; g < 3; ++g) hacc[g] = (f32x4){0.f, 0.f, 0.f, 0.f};
        #pragma unroll
        for (int ks = 0; ks < 4; ++ks) {
            bf16x8 a = *(const bf16x8*)(rd + c15 * HS + ks * 32 + q * 8);
            #pragma unroll
            for (int g = 0; g < 3; ++g) hacc[g] = mfma16(a, fhh[g][ks], hacc[g]);
        }
        #pragma unroll
        for (int r = 0; r < 4; ++r) {
            float rr = sigf((float)gR[r][0] + hacc[0][r] + Brz[0]);
            float zz = sigf((float)gR[r][1] + hacc[1][r] + Brz[1]);
            float nn = tanhf_((float)gR[r][2] + bin + rr * (hacc[2][r] + bhn));
            float hnew = zz * (hr[r] - nn) + nn;
            hr[r] = hnew;
            wr[(q * 4 + r) * HS + c_col] = (__bf16)hnew;
        }
        barrier_nodrain();
    };

    for (int tt = 0; tt < 128; ++tt) {
        step(hsA, hsB, gvA, gvB);
        step(hsB, hsA, gvB, gvA);
    }

    // ---- head: relu(h1 @ W1^T + b1) @ W2^T + b2 -> sigmoid ----------------
    #pragma unroll
    for (int r = 0; r < 4; ++r) h1f[(q * 4 + r) * 128 + c_col] = hr[r];
    __syncthreads();
    for (int p = tid; p < 16 * 64; p += 512) {
        int m = p >> 6, u = p & 63;
        float s = b1[u];
        const float* hrow = &h1f[m * 128];
        const float* wrow = &W1[u * 128];
        #pragma unroll 8
        for (int k = 0; k < 128; ++k) s += hrow[k] * wrow[k];
        hdnf[p] = fmaxf(s, 0.f);
    }
    __syncthreads();
    if (tid < 16) {
        float s = b2[0];
        #pragma unroll 8
        for (int k = 0; k < 64; ++k) s += hdnf[tid * 64 + k] * W2[k];
        out[b0 + tid] = sigf(s);
    }
}

// ---------------------------------------------------------------------------
extern "C" void kernel_launch(void* const* d_in, const int* in_sizes, int n_in,
                              void* d_out, int out_size, void* d_ws, size_t ws_size,
                              hipStream_t stream) {
    const float* x     = (const float*)d_in[0];
    const float* W_ih0 = (const float*)d_in[1];
    const float* W_hh0 = (const float*)d_in[2];
    const float* bih0  = (const float*)d_in[3];
    const float* bhh0  = (const float*)d_in[4];
    const float* W_ih1 = (const float*)d_in[5];
    const float* W_hh1 = (const float*)d_in[6];
    const float* bih1  = (const float*)d_in[7];
    const float* bhh1  = (const float*)d_in[8];
    const float* W1    = (const float*)d_in[9];
    const float* b1    = (const float*)d_in[10];
    const float* W2    = (const float*)d_in[11];
    const float* b2    = (const float*)d_in[12];
    float* out = (float*)d_out;

    char* ws = (char*)d_ws;
    // ws layout (bytes) — unchanged from round 2:
    //   gio   : 262144 x 384 bf16 = 201,326,592   @ 0   (gi0 -> h0 -> gi1, in place)
    //   Wih0b : 384x160 bf16      =     122,880   @ 201326592
    //   Whh0b / Wih1b / Whh1b : 384x128 bf16 = 98,304 each
    __bf16* gio   = (__bf16*)(ws);
    __bf16* wih0b = (__bf16*)(ws + 201326592);
    __bf16* whh0b = (__bf16*)(ws + 201449472);
    __bf16* wih1b = (__bf16*)(ws + 201547776);
    __bf16* whh1b = (__bf16*)(ws + 201646080);

    prep_w_kernel<<<240, 256, 0, stream>>>(W_ih0, W_hh0, W_ih1, W_hh1,
                                           wih0b, whh0b, wih1b, whh1b);
    gi0_gemm_kernel<<<2048, 512, 0, stream>>>(x, wih0b, gio);
    gru_rec0_kernel<<<64, 512, 0, stream>>>(gio, whh0b, bih0, bhh0);
    gi1_gemm_kernel<<<2048, 512, 0, stream>>>(gio, wih1b);
    gru_rec1_kernel<<<64, 512, 0, stream>>>(gio, whh1b, bih1, bhh1,
                                            W1, b1, W2, b2, out);
}

// Round 6
// 783.601 us; speedup vs baseline: 1.8164x; 1.1897x over previous
//
#include <hip/hip_runtime.h>

// ---------------------------------------------------------------------------
// TorchGRUClassifier: 2-layer GRU (B=1024, T=256, I=153, H=128) + MLP head.
// Round 9: attack gi0_gemm (268 us, 1.06 TB/s, all pipes idle -> latency).
//  (a) staging: batched 16B float4 loads over the block's linear x-panel
//      (78336 B, 16B-aligned for all blocks), magic-div scatter to LDS.
//      ~10 loads in flight before any ds_write (was: 40 rolled scalar loads).
//  (b) all __syncthreads -> lgkmcnt-only barrier (no vmcnt(0) store drains;
//      round-2 proved this wins in rec; epilogue had 5 draining barriers).
//  (c) A-tile LDS stride 160 -> 168 bf16 (336 B): bank stride 20 -> the 40
//      ds_read_b128/thread go 8-way-conflicted -> conflict-free
//      (SQ_LDS_BANK_CONFLICT 3.4M -> ~0).
// Layer-split structure from round 8 kept verbatim otherwise.
// ---------------------------------------------------------------------------

typedef __bf16 bf16x8 __attribute__((ext_vector_type(8)));
typedef __bf16 bf16x4 __attribute__((ext_vector_type(4)));
typedef float  f32x4  __attribute__((ext_vector_type(4)));

#define HS 136   // LDS row stride (bf16): 272 B -> conflict-free for rec/gi1
#define OS 136   // epilogue output-tile stride
#define AS 168   // gi0 A-tile stride (bf16): 336 B -> bank stride 20, clean

__device__ __forceinline__ f32x4 mfma16(bf16x8 a, bf16x8 b, f32x4 c) {
    return __builtin_amdgcn_mfma_f32_16x16x32_bf16(a, b, c, 0, 0, 0);
}
__device__ __forceinline__ float sigf(float x) {
    return __builtin_amdgcn_rcpf(1.f + __expf(-x));
}
__device__ __forceinline__ float tanhf_(float x) { return 2.f * sigf(2.f * x) - 1.f; }

// Workgroup barrier WITHOUT the vmcnt(0) drain __syncthreads() emits:
// LDS ordering via lgkmcnt(0); global loads/stores stay in flight across it.
__device__ __forceinline__ void barrier_nodrain() {
    asm volatile("s_waitcnt lgkmcnt(0)" ::: "memory");
    __builtin_amdgcn_s_barrier();
    asm volatile("" ::: "memory");
}

// ---- prep: cast weights to bf16 (W_ih0 padded K 153->160 with zeros) ------
__global__ void prep_w_kernel(const float* __restrict__ Wih0, const float* __restrict__ Whh0,
                              const float* __restrict__ Wih1, const float* __restrict__ Whh1,
                              __bf16* __restrict__ o_ih0, __bf16* __restrict__ o_hh0,
                              __bf16* __restrict__ o_ih1, __bf16* __restrict__ o_hh1) {
    int idx = blockIdx.x * 256 + threadIdx.x;      // grid covers 384*160 = 61440
    if (idx < 384 * 160) {
        int n = idx / 160, k = idx - n * 160;
        o_ih0[idx] = (__bf16)(k < 153 ? Wih0[n * 153 + k] : 0.f);
    }
    if (idx < 384 * 128) {
        o_hh0[idx] = (__bf16)Whh0[idx];
        o_ih1[idx] = (__bf16)Wih1[idx];
        o_hh1[idx] = (__bf16)Whh1[idx];
    }
}

// ---- gi0 GEMM: [262144,153(pad160)] x [160,384] -> gi0 bf16 [262144][384] --
__global__ __launch_bounds__(512, 2) void gi0_gemm_kernel(
    const float* __restrict__ x, const __bf16* __restrict__ Wih0b,
    __bf16* __restrict__ gi0)
{
    __shared__ __align__(16) __bf16 smem[128 * AS];   // A (42 KB), reused as Os
    const int r0  = blockIdx.x * 128;
    const int tid = threadIdx.x;
    const int w = tid >> 6, lane = tid & 63, q = lane >> 4, c15 = lane & 15;

    // B fragments first: these global loads overlap the x staging below.
    bf16x8 bf[3][5];
    #pragma unroll
    for (int j = 0; j < 3; ++j) {
        int colb = 16 * (w + 8 * j) + c15;
        #pragma unroll
        for (int ks = 0; ks < 5; ++ks)
            bf[j][ks] = *(const bf16x8*)(Wih0b + colb * 160 + ks * 32 + q * 8);
    }

    // ---- staging: panel = 128*153 f32 = 78336 B = 4896 16B chunks, aligned.
    const float* px = x + (size_t)r0 * 153;
    auto scatter = [&](unsigned c, f32x4 v) {
        unsigned m0  = 4u * c;
        unsigned row = m0 / 153u;            // magic-mul
        unsigned col = m0 - row * 153u;
        #pragma unroll
        for (int i = 0; i < 4; ++i) {
            unsigned cc = col + i, rr = row;
            if (cc >= 153u) { cc -= 153u; rr += 1u; }
            smem[rr * AS + cc] = (__bf16)v[i];
        }
    };
    // zero K-pad cols 153..159 (B is zero there, but 0*garbage = NaN hazard)
    #pragma unroll
    for (int p = tid; p < 896; p += 512)
        smem[(p / 7) * AS + 153 + p % 7] = (__bf16)0.f;
    {
        f32x4 v[5];
        #pragma unroll
        for (int k = 0; k < 5; ++k)
            v[k] = *(const f32x4*)(px + 4u * (tid + k * 512));
        #pragma unroll
        for (int k = 0; k < 5; ++k) scatter(tid + k * 512, v[k]);
        f32x4 u[4];
        #pragma unroll
        for (int k = 0; k < 4; ++k)
            u[k] = *(const f32x4*)(px + 4u * (tid + (5 + k) * 512));
        f32x4 tv;
        const bool tail = tid < 288;                 // 4896 = 9*512 + 288
        if (tail) tv = *(const f32x4*)(px + 4u * (tid + 4608));
        #pragma unroll
        for (int k = 0; k < 4; ++k) scatter(tid + (5 + k) * 512, u[k]);
        if (tail) scatter(tid + 4608, tv);
    }
    barrier_nodrain();

    f32x4 acc[8][3];
    #pragma unroll
    for (int rt = 0; rt < 8; ++rt)
        #pragma unroll
        for (int j = 0; j < 3; ++j) acc[rt][j] = (f32x4){0.f, 0.f, 0.f, 0.f};

    #pragma unroll
    for (int ks = 0; ks < 5; ++ks) {
        bf16x8 a[8];
        #pragma unroll
        for (int rt = 0; rt < 8; ++rt)
            a[rt] = *(const bf16x8*)(&smem[(rt * 16 + c15) * AS + ks * 32 + q * 8]);
        #pragma unroll
        for (int rt = 0; rt < 8; ++rt)
            #pragma unroll
            for (int j = 0; j < 3; ++j) acc[rt][j] = mfma16(a[rt], bf[j][ks], acc[rt][j]);
    }
    barrier_nodrain();   // done reading A; reuse as Os
    #pragma unroll
    for (int j = 0; j < 3; ++j) {
        #pragma unroll
        for (int rt = 0; rt < 8; ++rt)
            #pragma unroll
            for (int r = 0; r < 4; ++r)
                smem[(rt * 16 + q * 4 + r) * OS + 16 * w + c15] = (__bf16)acc[rt][j][r];
        barrier_nodrain();
        #pragma unroll
        for (int pass = 0; pass < 4; ++pass) {
            int row = pass * 32 + (tid >> 4);
            int col = (tid & 15) * 8;
            bf16x8 v = *(const bf16x8*)(&smem[row * OS + col]);
            *(bf16x8*)(gi0 + (size_t)(r0 + row) * 384 + j * 128 + col) = v;
        }
        if (j < 2) barrier_nodrain();
    }
}

// ---- rec0: layer-0 recurrence; h0_t written in-place into gio rows --------
__global__ __launch_bounds__(512, 2)
void gru_rec0_kernel(__bf16* __restrict__ gio,      // gi0 in; h0 out (cols 0..127)
                     const __bf16* __restrict__ Whh0,
                     const float* __restrict__ b_ih0, const float* __restrict__ b_hh0)
{
    __shared__ __align__(16) __bf16 hsA[16 * HS], hsB[16 * HS];

    const int tid  = threadIdx.x;
    const int w    = tid >> 6;
    const int lane = tid & 63;
    const int q    = lane >> 4;
    const int c15  = lane & 15;
    const int c_col = w * 16 + c15;
    const int b0   = blockIdx.x * 16;

    bf16x8 fhh[3][4];
    #pragma unroll
    for (int g = 0; g < 3; ++g)
        #pragma unroll
        for (int ks = 0; ks < 4; ++ks)
            fhh[g][ks] = *(const bf16x8*)(Whh0 + (size_t)(g * 128 + c_col) * 128 + ks * 32 + q * 8);

    float Brz[2], bin, bhn;
    Brz[0] = b_ih0[c_col] + b_hh0[c_col];
    Brz[1] = b_ih0[128 + c_col] + b_hh0[128 + c_col];
    bin = b_ih0[256 + c_col]; bhn = b_hh0[256 + c_col];

    float hr[4] = {0.f, 0.f, 0.f, 0.f};
    for (int i = tid; i < 16 * HS; i += 512) { hsA[i] = (__bf16)0.f; hsB[i] = (__bf16)0.f; }
    __syncthreads();

    unsigned goff[4];
    #pragma unroll
    for (int r = 0; r < 4; ++r)
        goff[r] = (unsigned)(b0 + q * 4 + r) * 98304u + (unsigned)c_col;   // 98304 = 256*384

    __bf16 gvA[4][3], gvB[4][3];
    #pragma unroll
    for (int r = 0; r < 4; ++r)
        #pragma unroll
        for (int g = 0; g < 3; ++g) gvA[r][g] = gio[goff[r] + g * 128];
    #pragma unroll
    for (int r = 0; r < 4; ++r) goff[r] += 384;

    const int srow = tid >> 5;            // 0..15
    const int scol = (tid & 31) * 4;      // 0..124
    const size_t sbase = (size_t)(b0 + srow) * 98304u + scol;

    auto step = [&](const __bf16* rd, __bf16* wr,
                    __bf16 (&gR)[4][3], __bf16 (&gW)[4][3], int t) {
        #pragma unroll
        for (int r = 0; r < 4; ++r)
            #pragma unroll
            for (int g = 0; g < 3; ++g) gW[r][g] = gio[goff[r] + g * 128];
        #pragma unroll
        for (int r = 0; r < 4; ++r) goff[r] += 384;

        f32x4 hacc[3];
        #pragma unroll
        for (int g = 0; g < 3; ++g) hacc[g] = (f32x4){0.f, 0.f, 0.f, 0.f};
        #pragma unroll
        for (int ks = 0; ks < 4; ++ks) {
            bf16x8 a = *(const bf16x8*)(rd + c15 * HS + ks * 32 + q * 8);
            #pragma unroll
            for (int g = 0; g < 3; ++g) hacc[g] = mfma16(a, fhh[g][ks], hacc[g]);
        }
        #pragma unroll
        for (int r = 0; r < 4; ++r) {
            float rr = sigf((float)gR[r][0] + hacc[0][r] + Brz[0]);
            float zz = sigf((float)gR[r][1] + hacc[1][r] + Brz[1]);
            float nn = tanhf_((float)gR[r][2] + bin + rr * (hacc[2][r] + bhn));
            float hnew = zz * (hr[r] - nn) + nn;
            hr[r] = hnew;
            wr[(q * 4 + r) * HS + c_col] = (__bf16)hnew;
        }
        barrier_nodrain();
        bf16x4 hv = *(const bf16x4*)(wr + srow * HS + scol);
        *(bf16x4*)(gio + sbase + (size_t)t * 384) = hv;
    };

    for (int tt = 0; tt < 128; ++tt) {
        step(hsA, hsB, gvA, gvB, 2 * tt);
        step(hsB, hsA, gvB, gvA, 2 * tt + 1);
    }
}

// ---- gi1 GEMM (in-place): rows [0:128]=h0 -> rows [0:384]=gi1 -------------
__global__ __launch_bounds__(512, 2)
void gi1_gemm_kernel(__bf16* __restrict__ gio, const __bf16* __restrict__ Wih1b)
{
    __shared__ __align__(16) __bf16 smem[128 * HS];   // A (34 KB), reused as Os
    const int r0  = blockIdx.x * 128;
    const int tid = threadIdx.x;
    const int w = tid >> 6, lane = tid & 63, q = lane >> 4, c15 = lane & 15;

    bf16x8 bf[3][4];
    #pragma unroll
    for (int j = 0; j < 3; ++j) {
        int colb = 16 * (w + 8 * j) + c15;
        #pragma unroll
        for (int ks = 0; ks < 4; ++ks)
            bf[j][ks] = *(const bf16x8*)(Wih1b + (size_t)colb * 128 + ks * 32 + q * 8);
    }

    // stage A: 128x128 bf16, batched 16B loads then writes
    {
        bf16x8 av[4];
        #pragma unroll
        for (int k = 0; k < 4; ++k) {
            int cidx = tid + k * 512;
            int row = cidx >> 4, c8 = (cidx & 15) * 8;
            av[k] = *(const bf16x8*)(gio + (size_t)(r0 + row) * 384 + c8);
        }
        #pragma unroll
        for (int k = 0; k < 4; ++k) {
            int cidx = tid + k * 512;
            int row = cidx >> 4, c8 = (cidx & 15) * 8;
            *(bf16x8*)&smem[row * HS + c8] = av[k];
        }
    }
    barrier_nodrain();

    f32x4 acc[8][3];
    #pragma unroll
    for (int rt = 0; rt < 8; ++rt)
        #pragma unroll
        for (int j = 0; j < 3; ++j) acc[rt][j] = (f32x4){0.f, 0.f, 0.f, 0.f};

    #pragma unroll
    for (int ks = 0; ks < 4; ++ks) {
        bf16x8 a[8];
        #pragma unroll
        for (int rt = 0; rt < 8; ++rt)
            a[rt] = *(const bf16x8*)(&smem[(rt * 16 + c15) * HS + ks * 32 + q * 8]);
        #pragma unroll
        for (int rt = 0; rt < 8; ++rt)
            #pragma unroll
            for (int j = 0; j < 3; ++j) acc[rt][j] = mfma16(a[rt], bf[j][ks], acc[rt][j]);
    }
    barrier_nodrain();   // done reading A; rows may now be overwritten
    #pragma unroll
    for (int j = 0; j < 3; ++j) {
        #pragma unroll
        for (int rt = 0; rt < 8; ++rt)
            #pragma unroll
            for (int r = 0; r < 4; ++r)
                smem[(rt * 16 + q * 4 + r) * OS + 16 * w + c15] = (__bf16)acc[rt][j][r];
        barrier_nodrain();
        #pragma unroll
        for (int pass = 0; pass < 4; ++pass) {
            int row = pass * 32 + (tid >> 4);
            int col = (tid & 15) * 8;
            bf16x8 v = *(const bf16x8*)(&smem[row * OS + col]);
            *(bf16x8*)(gio + (size_t)(r0 + row) * 384 + j * 128 + col) = v;
        }
        if (j < 2) barrier_nodrain();
    }
}

// ---- rec1: layer-1 recurrence + MLP head ----------------------------------
__global__ __launch_bounds__(512, 2)
void gru_rec1_kernel(const __bf16* __restrict__ gi1,
                     const __bf16* __restrict__ Whh1,
                     const float* __restrict__ b_ih1, const float* __restrict__ b_hh1,
                     const float* __restrict__ W1, const float* __restrict__ b1,
                     const float* __restrict__ W2, const float* __restrict__ b2,
                     float* __restrict__ out)
{
    __shared__ __align__(16) __bf16 hsA[16 * HS], hsB[16 * HS];
    __shared__ float h1f[16 * 128];
    __shared__ float hdnf[16 * 64];

    const int tid  = threadIdx.x;
    const int w    = tid >> 6;
    const int lane = tid & 63;
    const int q    = lane >> 4;
    const int c15  = lane & 15;
    const int c_col = w * 16 + c15;
    const int b0   = blockIdx.x * 16;

    bf16x8 fhh[3][4];
    #pragma unroll
    for (int g = 0; g < 3; ++g)
        #pragma unroll
        for (int ks = 0; ks < 4; ++ks)
            fhh[g][ks] = *(const bf16x8*)(Whh1 + (size_t)(g * 128 + c_col) * 128 + ks * 32 + q * 8);

    float Brz[2], bin, bhn;
    Brz[0] = b_ih1[c_col] + b_hh1[c_col];
    Brz[1] = b_ih1[128 + c_col] + b_hh1[128 + c_col];
    bin = b_ih1[256 + c_col]; bhn = b_hh1[256 + c_col];

    float hr[4] = {0.f, 0.f, 0.f, 0.f};
    for (int i = tid; i < 16 * HS; i += 512) { hsA[i] = (__bf16)0.f; hsB[i] = (__bf16)0.f; }
    __syncthreads();

    unsigned goff[4];
    #pragma unroll
    for (int r = 0; r < 4; ++r)
        goff[r] = (unsigned)(b0 + q * 4 + r) * 98304u + (unsigned)c_col;

    __bf16 gvA[4][3], gvB[4][3];
    #pragma unroll
    for (int r = 0; r < 4; ++r)
        #pragma unroll
        for (int g = 0; g < 3; ++g) gvA[r][g] = gi1[goff[r] + g * 128];
    #pragma unroll
    for (int r = 0; r < 4; ++r) goff[r] += 384;

    auto step = [&](const __bf16* rd, __bf16* wr,
                    __bf16 (&gR)[4][3], __bf16 (&gW)[4][3]) {
        #pragma unroll
        for (int r = 0; r < 4; ++r)
            #pragma unroll
            for (int g = 0; g < 3; ++g) gW[r][g] = gi1[goff[r] + g * 128];
        #pragma unroll
        for (int r = 0; r < 4; ++r) goff[r] += 384;

        f32x4 hacc[3];
        #pragma unroll
        for (int g = 0; g < 3; ++g) hacc[g] = (f32x4){0.f, 0.f, 0.f, 0.f};
        #pragma unroll
        for (int ks = 0; ks < 4; ++ks) {
            bf16x8 a = *(const bf16x8*)(rd + c15 * HS + ks * 32 + q * 8);
            #pragma unroll
            for (int g = 0; g < 3; ++g) hacc[g] = mfma16(a, fhh[g][ks], hacc[g]);
        }
        #pragma unroll
        for (int r = 0; r < 4; ++r) {
            float rr = sigf((float)gR[r][0] + hacc[0][r] + Brz[0]);
            float zz = sigf((float)gR[r][1] + hacc[1][r] + Brz[1]);
            float nn = tanhf_((float)gR[r][2] + bin + rr * (hacc[2][r] + bhn));
            float hnew = zz * (hr[r] - nn) + nn;
            hr[r] = hnew;
            wr[(q * 4 + r) * HS + c_col] = (__bf16)hnew;
        }
        barrier_nodrain();
    };

    for (int tt = 0; tt < 128; ++tt) {
        step(hsA, hsB, gvA, gvB);
        step(hsB, hsA, gvB, gvA);
    }

    // ---- head: relu(h1 @ W1^T + b1) @ W2^T + b2 -> sigmoid ----------------
    #pragma unroll
    for (int r = 0; r < 4; ++r) h1f[(q * 4 + r) * 128 + c_col] = hr[r];
    __syncthreads();
    for (int p = tid; p < 16 * 64; p += 512) {
        int m = p >> 6, u = p & 63;
        float s = b1[u];
        const float* hrow = &h1f[m * 128];
        const float* wrow = &W1[u * 128];
        #pragma unroll 8
        for (int k = 0; k < 128; ++k) s += hrow[k] * wrow[k];
        hdnf[p] = fmaxf(s, 0.f);
    }
    __syncthreads();
    if (tid < 16) {
        float s = b2[0];
        #pragma unroll 8
        for (int k = 0; k < 64; ++k) s += hdnf[tid * 64 + k] * W2[k];
        out[b0 + tid] = sigf(s);
    }
}

// ---------------------------------------------------------------------------
extern "C" void kernel_launch(void* const* d_in, const int* in_sizes, int n_in,
                              void* d_out, int out_size, void* d_ws, size_t ws_size,
                              hipStream_t stream) {
    const float* x     = (const float*)d_in[0];
    const float* W_ih0 = (const float*)d_in[1];
    const float* W_hh0 = (const float*)d_in[2];
    const float* bih0  = (const float*)d_in[3];
    const float* bhh0  = (const float*)d_in[4];
    const float* W_ih1 = (const float*)d_in[5];
    const float* W_hh1 = (const float*)d_in[6];
    const float* bih1  = (const float*)d_in[7];
    const float* bhh1  = (const float*)d_in[8];
    const float* W1    = (const float*)d_in[9];
    const float* b1    = (const float*)d_in[10];
    const float* W2    = (const float*)d_in[11];
    const float* b2    = (const float*)d_in[12];
    float* out = (float*)d_out;

    char* ws = (char*)d_ws;
    // ws layout (bytes):
    //   gio   : 262144 x 384 bf16 = 201,326,592   @ 0   (gi0 -> h0 -> gi1, in place)
    //   Wih0b : 384x160 bf16      =     122,880   @ 201326592
    //   Whh0b / Wih1b / Whh1b : 384x128 bf16 = 98,304 each
    __bf16* gio   = (__bf16*)(ws);
    __bf16* wih0b = (__bf16*)(ws + 201326592);
    __bf16* whh0b = (__bf16*)(ws + 201449472);
    __bf16* wih1b = (__bf16*)(ws + 201547776);
    __bf16* whh1b = (__bf16*)(ws + 201646080);

    prep_w_kernel<<<240, 256, 0, stream>>>(W_ih0, W_hh0, W_ih1, W_hh1,
                                           wih0b, whh0b, wih1b, whh1b);
    gi0_gemm_kernel<<<2048, 512, 0, stream>>>(x, wih0b, gio);
    gru_rec0_kernel<<<64, 512, 0, stream>>>(gio, whh0b, bih0, bhh0);
    gi1_gemm_kernel<<<2048, 512, 0, stream>>>(gio, wih1b);
    gru_rec1_kernel<<<64, 512, 0, stream>>>(gio, whh1b, bih1, bhh1,
                                            W1, b1, W2, b2, out);
}